// Round 1
// baseline (131.075 us; speedup 1.0000x reference)
//
#include <hip/hip_runtime.h>
#include <hip/hip_bf16.h>
#include <math.h>

typedef __attribute__((ext_vector_type(8))) __bf16 bf16x8;
typedef __attribute__((ext_vector_type(4))) float f32x4;
typedef __attribute__((ext_vector_type(8))) unsigned short u16x8;

#define LDS_STRIDE 136  // 128 + 8 pad (ushorts): row stride 272B -> 2-way LDS aliasing (free)

__device__ __forceinline__ float sigmoid_f(float v) {
  return __builtin_amdgcn_rcpf(1.f + __expf(-v));
}
__device__ __forceinline__ float tanh_f(float z) {
  float az = fabsf(z);
  float e = __expf(-2.f * az);
  float t = (1.f - e) * __builtin_amdgcn_rcpf(1.f + e);
  return copysignf(t, z);
}
__device__ __forceinline__ bf16x8 cvt8(float4 a, float4 b) {
  bf16x8 r;
  r[0] = (__bf16)a.x; r[1] = (__bf16)a.y; r[2] = (__bf16)a.z; r[3] = (__bf16)a.w;
  r[4] = (__bf16)b.x; r[5] = (__bf16)b.y; r[6] = (__bf16)b.z; r[7] = (__bf16)b.w;
  return r;
}

// Pack W_x/W_h fp32 -> bf16 into 6 matrices of 128x128 (k-contiguous) in pass order:
// 0: Wx_r  1: Wh_r  2: Wh_h  3: Wx_h  4: Wx_u  5: Wh_u
__global__ void pack_weights_kernel(const float* __restrict__ Wx,
                                    const float* __restrict__ Wh,
                                    unsigned short* __restrict__ wp) {
  int t = blockIdx.x * 256 + threadIdx.x;
  if (t >= 12288) return;          // 6 * 128 * 16 chunks of 8 elems
  int m = t >> 11;
  int ci = t & 2047;               // chunk within matrix: n = ci>>4, c = ci&15
  int n = ci >> 4;
  const float* src; int ro;
  switch (m) {
    case 0: src = Wx; ro = 128; break;
    case 1: src = Wh; ro = 128; break;
    case 2: src = Wh; ro = 256; break;
    case 3: src = Wx; ro = 256; break;
    case 4: src = Wx; ro = 0;   break;
    default: src = Wh; ro = 0;  break;
  }
  const float* p = src + (ro + n) * 128 + (ci & 15) * 8;
  float4 a = *(const float4*)p;
  float4 b = *(const float4*)(p + 4);
  bf16x8 v = cvt8(a, b);
  *(bf16x8*)(wp + m * 16384 + ci * 8) = v;
}

__global__ __launch_bounds__(256, 2) void augru_kernel(
    const float* __restrict__ x, const float* __restrict__ hp,
    const float* __restrict__ att, const unsigned short* __restrict__ wp,
    const float* __restrict__ bx, const float* __restrict__ bh,
    float* __restrict__ out) {
  __shared__ unsigned short wlds[128 * LDS_STRIDE];
  const int tid  = threadIdx.x;
  const int wave = tid >> 6;
  const int lane = tid & 63;
  const int quad = lane >> 4;
  const int l15  = lane & 15;
  const int rb   = blockIdx.x * 64 + wave * 16;  // this wave's 16-row M-tile

  // ---- A fragments straight from global fp32, converted to bf16 in regs.
  // A[m=l15][k=quad*8+j] per 16x16x32 K-tile; 4 K-tiles cover K=128.
  bf16x8 xf[4], hf[4];
  {
    const float* xr = x  + (rb + l15) * 128;
    const float* hr = hp + (rb + l15) * 128;
#pragma unroll
    for (int kt = 0; kt < 4; ++kt) {
      int off = kt * 32 + quad * 8;
      float4 a = *(const float4*)(xr + off);
      float4 b = *(const float4*)(xr + off + 4);
      xf[kt] = cvt8(a, b);
    }
#pragma unroll
    for (int kt = 0; kt < 4; ++kt) {
      int off = kt * 32 + quad * 8;
      float4 a = *(const float4*)(hr + off);
      float4 b = *(const float4*)(hr + off + 4);
      hf[kt] = cvt8(a, b);
    }
  }

  // ---- weight staging: chunk ci = i*256+tid -> LDS row i*16+(tid>>4), chunk tid&15
  const int sn = tid >> 4;
  const int sc = tid & 15;
  u16x8 wreg[8];
#pragma unroll
  for (int i = 0; i < 8; ++i)
    wreg[i] = *(const u16x8*)(wp + (i * 256 + tid) * 8);
#pragma unroll
  for (int i = 0; i < 8; ++i)
    *(u16x8*)&wlds[(i * 16 + sn) * LDS_STRIDE + sc * 8] = wreg[i];
  __syncthreads();

  f32x4 acc[8], keep[8];
#pragma unroll
  for (int nt = 0; nt < 8; ++nt) acc[nt] = (f32x4)0.f;

  auto gemm = [&](const bf16x8* af) {
#pragma unroll
    for (int nt = 0; nt < 8; ++nt) {
#pragma unroll
      for (int kt = 0; kt < 4; ++kt) {
        bf16x8 bfrag = *(const bf16x8*)&wlds[(nt * 16 + l15) * LDS_STRIDE + (kt * 4 + quad) * 8];
        acc[nt] = __builtin_amdgcn_mfma_f32_16x16x32_bf16(af[kt], bfrag, acc[nt], 0, 0, 0);
      }
    }
  };
  auto preload = [&](int m) {
#pragma unroll
    for (int i = 0; i < 8; ++i)
      wreg[i] = *(const u16x8*)(wp + m * 16384 + (i * 256 + tid) * 8);
  };
  auto commit = [&]() {
    __syncthreads();
#pragma unroll
    for (int i = 0; i < 8; ++i)
      *(u16x8*)&wlds[(i * 16 + sn) * LDS_STRIDE + sc * 8] = wreg[i];
    __syncthreads();
  };

  // pass 0: x . Wx_r
  preload(1); gemm(xf); commit();
  // pass 1: + h . Wh_r  -> r
  preload(2); gemm(hf);
#pragma unroll
  for (int nt = 0; nt < 8; ++nt) {
    int col = nt * 16 + l15;
    float br = bx[128 + col] + bh[128 + col];
#pragma unroll
    for (int r = 0; r < 4; ++r) keep[nt][r] = sigmoid_f(acc[nt][r] + br);
    acc[nt] = (f32x4)0.f;
  }
  commit();
  // pass 2: h . Wh_h -> t = r * (g + bh_h)
  preload(3); gemm(hf);
#pragma unroll
  for (int nt = 0; nt < 8; ++nt) {
    int col = nt * 16 + l15;
    float bhh = bh[256 + col];
#pragma unroll
    for (int r = 0; r < 4; ++r) keep[nt][r] = keep[nt][r] * (acc[nt][r] + bhh);
    acc[nt] = (f32x4)0.f;
  }
  commit();
  // pass 3: x . Wx_h -> h_tilde = tanh(g + bx_h + t)
  preload(4); gemm(xf);
#pragma unroll
  for (int nt = 0; nt < 8; ++nt) {
    int col = nt * 16 + l15;
    float bxh = bx[256 + col];
#pragma unroll
    for (int r = 0; r < 4; ++r) keep[nt][r] = tanh_f(acc[nt][r] + bxh + keep[nt][r]);
    acc[nt] = (f32x4)0.f;
  }
  commit();
  // pass 4: x . Wx_u
  preload(5); gemm(xf); commit();
  // pass 5: + h . Wh_u -> u, blend, store
  gemm(hf);

  float atts[4];
#pragma unroll
  for (int r = 0; r < 4; ++r) atts[r] = att[rb + quad * 4 + r];
#pragma unroll
  for (int nt = 0; nt < 8; ++nt) {
    int col = nt * 16 + l15;
    float bu = bx[col] + bh[col];
#pragma unroll
    for (int r = 0; r < 4; ++r) {
      int row = rb + quad * 4 + r;
      float u  = sigmoid_f(acc[nt][r] + bu);
      float ua = atts[r] * u;
      float h0 = hp[row * 128 + col];
      out[row * 128 + col] = fmaf(ua, keep[nt][r] - h0, h0);  // (1-ua)*h0 + ua*ht
    }
  }
}

extern "C" void kernel_launch(void* const* d_in, const int* in_sizes, int n_in,
                              void* d_out, int out_size, void* d_ws, size_t ws_size,
                              hipStream_t stream) {
  const float* x   = (const float*)d_in[0];
  const float* hpv = (const float*)d_in[1];
  const float* att = (const float*)d_in[2];
  const float* Wx  = (const float*)d_in[3];
  const float* bx  = (const float*)d_in[4];
  const float* Wh  = (const float*)d_in[5];
  const float* bh  = (const float*)d_in[6];
  float* out = (float*)d_out;
  unsigned short* wp = (unsigned short*)d_ws;  // needs 196,608 B of scratch

  pack_weights_kernel<<<48, 256, 0, stream>>>(Wx, Wh, wp);
  augru_kernel<<<1024, 256, 0, stream>>>(x, hpv, att, wp, bx, bh, out);
}